// Round 1
// baseline (2561.564 us; speedup 1.0000x reference)
//
#include <hip/hip_runtime.h>
#include <hip/hip_bf16.h>

typedef __attribute__((ext_vector_type(4))) float f32x4;
typedef __attribute__((ext_vector_type(8))) short short8;
typedef __attribute__((ext_vector_type(8))) __bf16 bf16x8;

union FragU { bf16x8 h; short8 s; };

// ---------------------------------------------------------------------------
// Big GEMM: C[M][64] = A[M][K] (f32, row-major) @ BT[64][K]^T (bf16)
// 4 waves/block, 128 rows/block, mfma_f32_16x16x32_bf16, no LDS.
// A loaded f32 and converted in-register; both A and B fragments use the same
// contiguous-8 per-lane k order, so operand-layout k-permutation cancels.
// ---------------------------------------------------------------------------
__global__ __launch_bounds__(256) void gemm_adj(
    const float* __restrict__ A, const __bf16* __restrict__ BT,
    float* __restrict__ C, int M, int K)
{
  const int wave = threadIdx.x >> 6;
  const int lane = threadIdx.x & 63;
  const int r = lane & 15;   // row-in-mtile / col-in-ntile
  const int g = lane >> 4;   // k-group (0..3)
  const int rowBase = blockIdx.x * 128 + wave * 32;

  f32x4 acc[2][4];
  #pragma unroll
  for (int m = 0; m < 2; ++m)
    #pragma unroll
    for (int n = 0; n < 4; ++n)
      acc[m][n] = (f32x4){0.f, 0.f, 0.f, 0.f};

  const float* aPtr[2];
  #pragma unroll
  for (int m = 0; m < 2; ++m) {
    int row = rowBase + m * 16 + r;
    if (row >= M) row = M - 1;              // clamp; stores are guarded
    aPtr[m] = A + (size_t)row * K + g * 8;
  }
  const __bf16* bPtr[4];
  #pragma unroll
  for (int n = 0; n < 4; ++n)
    bPtr[n] = BT + (size_t)(n * 16 + r) * K + g * 8;

  const int kEnd = K & ~31;  // K is a multiple of 8; tail step only if K%32

  for (int k0 = 0; k0 < kEnd; k0 += 32) {
    FragU bf[4], af[2];
    #pragma unroll
    for (int n = 0; n < 4; ++n)
      bf[n].s = *(const short8*)(bPtr[n] + k0);
    #pragma unroll
    for (int m = 0; m < 2; ++m) {
      f32x4 a0 = *(const f32x4*)(aPtr[m] + k0);
      f32x4 a1 = *(const f32x4*)(aPtr[m] + k0 + 4);
      bf16x8 h;
      h[0] = (__bf16)a0[0]; h[1] = (__bf16)a0[1];
      h[2] = (__bf16)a0[2]; h[3] = (__bf16)a0[3];
      h[4] = (__bf16)a1[0]; h[5] = (__bf16)a1[1];
      h[6] = (__bf16)a1[2]; h[7] = (__bf16)a1[3];
      af[m].h = h;
    }
    #pragma unroll
    for (int m = 0; m < 2; ++m)
      #pragma unroll
      for (int n = 0; n < 4; ++n)
        acc[m][n] = __builtin_amdgcn_mfma_f32_16x16x32_bf16(
            af[m].s, bf[n].s, acc[m][n], 0, 0, 0);
  }

  if (kEnd < K) {            // guarded tail (per-lane 8-chunk is all-in or all-out)
    const int k0 = kEnd;
    const bool ok = (k0 + g * 8) < K;
    FragU bf[4], af[2];
    const short8 z = {0, 0, 0, 0, 0, 0, 0, 0};
    #pragma unroll
    for (int n = 0; n < 4; ++n)
      bf[n].s = ok ? *(const short8*)(bPtr[n] + k0) : z;
    #pragma unroll
    for (int m = 0; m < 2; ++m) {
      if (ok) {
        f32x4 a0 = *(const f32x4*)(aPtr[m] + k0);
        f32x4 a1 = *(const f32x4*)(aPtr[m] + k0 + 4);
        bf16x8 h;
        h[0] = (__bf16)a0[0]; h[1] = (__bf16)a0[1];
        h[2] = (__bf16)a0[2]; h[3] = (__bf16)a0[3];
        h[4] = (__bf16)a1[0]; h[5] = (__bf16)a1[1];
        h[6] = (__bf16)a1[2]; h[7] = (__bf16)a1[3];
        af[m].h = h;
      } else {
        af[m].s = z;
      }
    }
    #pragma unroll
    for (int m = 0; m < 2; ++m)
      #pragma unroll
      for (int n = 0; n < 4; ++n)
        acc[m][n] = __builtin_amdgcn_mfma_f32_16x16x32_bf16(
            af[m].s, bf[n].s, acc[m][n], 0, 0, 0);
  }

  // C/D layout: col = lane&15, row = (lane>>4)*4 + reg
  #pragma unroll
  for (int m = 0; m < 2; ++m) {
    #pragma unroll
    for (int j = 0; j < 4; ++j) {
      const int row = rowBase + m * 16 + g * 4 + j;
      if (row < M) {
        #pragma unroll
        for (int n = 0; n < 4; ++n)
          C[(size_t)row * 64 + n * 16 + r] = acc[m][n][j];
      }
    }
  }
}

// ---------------------------------------------------------------------------
// Transpose + f32->bf16 convert: in[K][64] f32 -> out[64][K] bf16
// ---------------------------------------------------------------------------
__global__ __launch_bounds__(256) void transpose_cvt(
    const float* __restrict__ in, __bf16* __restrict__ out, int K)
{
  __shared__ float tile[64][65];
  const int t = threadIdx.x;
  const int k0 = blockIdx.x * 64;
  #pragma unroll
  for (int i = 0; i < 4; ++i) {
    int f = t + i * 256;           // float4 index within 64x64 tile
    int k = f >> 4;                // 0..63
    int cc = (f & 15) << 2;        // 0..60
    if (k0 + k < K) {
      f32x4 v = *(const f32x4*)(in + (size_t)(k0 + k) * 64 + cc);
      tile[k][cc + 0] = v[0]; tile[k][cc + 1] = v[1];
      tile[k][cc + 2] = v[2]; tile[k][cc + 3] = v[3];
    }
  }
  __syncthreads();
  const int c = t >> 2;            // 0..63 output row
  const int kc = (t & 3) << 4;     // 0,16,32,48
  #pragma unroll
  for (int h = 0; h < 2; ++h) {
    int kk = kc + h * 8;
    if (k0 + kk < K) {             // 8-chunks are all-in or all-out (K % 8 == 0)
      FragU p;
      #pragma unroll
      for (int j = 0; j < 8; ++j) p.h[j] = (__bf16)tile[kk + j][c];
      *(short8*)(out + (size_t)c * K + k0 + kk) = p.s;
    }
  }
}

// ---------------------------------------------------------------------------
// out[i][c] = LeakyReLU( sum_k (pre[i][k]+self[i][k]) * W[c][k] + 2*b[c] )
// ---------------------------------------------------------------------------
__global__ __launch_bounds__(256) void layer_update(
    const float* __restrict__ pre, const float* __restrict__ self,
    const float* __restrict__ W, const float* __restrict__ b,
    float* __restrict__ out, int M)
{
  __shared__ float xs[4][64];
  const int t = threadIdx.x;
  const int c = t & 63;
  const int grp = t >> 6;
  const int row = blockIdx.x * 4 + grp;
  if (row < M)
    xs[grp][c] = pre[(size_t)row * 64 + c] + self[(size_t)row * 64 + c];
  __syncthreads();
  if (row >= M) return;
  float acc = 0.f;
  const f32x4* Wc = (const f32x4*)(W + c * 64);
  #pragma unroll
  for (int k4 = 0; k4 < 16; ++k4) {
    f32x4 w = Wc[k4];
    acc += xs[grp][k4 * 4 + 0] * w[0] + xs[grp][k4 * 4 + 1] * w[1]
         + xs[grp][k4 * 4 + 2] * w[2] + xs[grp][k4 * 4 + 3] * w[3];
  }
  float v = acc + 2.0f * b[c];
  out[(size_t)row * 64 + c] = (v > 0.f) ? v : 0.01f * v;
}

// ---------------------------------------------------------------------------
// scores[b] = sum_l sum_e u_l[uid[b]][e]*m_l[mid[b]][e]*outW[l*64+e] + outb
// one wave per interaction
// ---------------------------------------------------------------------------
__global__ __launch_bounds__(256) void gather_score(
    const int* __restrict__ uid, const int* __restrict__ mid,
    const float* __restrict__ u0, const float* __restrict__ u1,
    const float* __restrict__ u2, const float* __restrict__ u3,
    const float* __restrict__ m0, const float* __restrict__ m1,
    const float* __restrict__ m2, const float* __restrict__ m3,
    const float* __restrict__ oW, const float* __restrict__ ob,
    float* __restrict__ scores, int B)
{
  const int wave = threadIdx.x >> 6;
  const int lane = threadIdx.x & 63;
  const int b = blockIdx.x * 4 + wave;
  if (b >= B) return;
  const size_t ub = (size_t)uid[b] * 64 + lane;
  const size_t mb = (size_t)mid[b] * 64 + lane;
  float acc = u0[ub] * m0[mb] * oW[lane]
            + u1[ub] * m1[mb] * oW[64 + lane]
            + u2[ub] * m2[mb] * oW[128 + lane]
            + u3[ub] * m3[mb] * oW[192 + lane];
  #pragma unroll
  for (int off = 32; off > 0; off >>= 1)
    acc += __shfl_down(acc, off, 64);
  if (lane == 0) scores[b] = acc + ob[0];
}

// ---------------------------------------------------------------------------
extern "C" void kernel_launch(void* const* d_in, const int* in_sizes, int n_in,
                              void* d_out, int out_size, void* d_ws, size_t ws_size,
                              hipStream_t stream)
{
  const float* user_adj  = (const float*)d_in[0];
  const float* movie_adj = (const float*)d_in[1];
  const int*   user_id   = (const int*)d_in[2];
  const int*   movie_id  = (const int*)d_in[3];
  const float* user_emb  = (const float*)d_in[4];
  const float* movie_emb = (const float*)d_in[5];
  const float* user_Ws   = (const float*)d_in[6];
  const float* user_bs   = (const float*)d_in[7];
  const float* movie_Ws  = (const float*)d_in[8];
  const float* movie_bs  = (const float*)d_in[9];
  const float* out_W     = (const float*)d_in[10];
  const float* out_b     = (const float*)d_in[11];

  const int NU = 20000, NM = 10000, E = 64, B = 8192;

  char* ws = (char*)d_ws;
  float*  u_pre = (float*)(ws);                   // 20000*64 f32 = 5,120,000 B
  float*  m_pre = (float*)(ws + 5120000);         // 10000*64 f32 = 2,560,000 B
  float*  u1    = (float*)(ws + 7680000);         // 5,120,000 B
  float*  u2    = (float*)(ws + 12800000);        // 5,120,000 B
  float*  m1    = (float*)(ws + 17920000);        // 2,560,000 B
  float*  m2    = (float*)(ws + 20480000);        // 2,560,000 B
  __bf16* uT    = (__bf16*)(ws + 23040000);       // 64*20000 bf16 = 2,560,000 B
  __bf16* mT    = (__bf16*)(ws + 25600000);       // 64*10000 bf16 = 1,280,000 B

  float* scores = (float*)d_out;
  float* u3 = scores + B;            // [20000,64]
  float* m3 = u3 + (size_t)NU * E;   // [10000,64]

  const float* uCur = user_emb;
  const float* mCur = movie_emb;
  for (int l = 0; l < 3; ++l) {
    float* uNext = (l == 0) ? u1 : (l == 1) ? u2 : u3;
    float* mNext = (l == 0) ? m1 : (l == 1) ? m2 : m3;
    transpose_cvt<<<(NM + 63) / 64, 256, 0, stream>>>(mCur, mT, NM);
    transpose_cvt<<<(NU + 63) / 64, 256, 0, stream>>>(uCur, uT, NU);
    gemm_adj<<<(NU + 127) / 128, 256, 0, stream>>>(user_adj, mT, u_pre, NU, NM);
    gemm_adj<<<(NM + 127) / 128, 256, 0, stream>>>(movie_adj, uT, m_pre, NM, NU);
    layer_update<<<(NU + 3) / 4, 256, 0, stream>>>(
        u_pre, uCur, user_Ws + (size_t)l * E * E, user_bs + (size_t)l * E, uNext, NU);
    layer_update<<<(NM + 3) / 4, 256, 0, stream>>>(
        m_pre, mCur, movie_Ws + (size_t)l * E * E, movie_bs + (size_t)l * E, mNext, NM);
    uCur = uNext; mCur = mNext;
  }
  gather_score<<<(B + 3) / 4, 256, 0, stream>>>(
      user_id, movie_id, user_emb, u1, u2, u3,
      movie_emb, m1, m2, m3, out_W, out_b, scores, B);
}

// Round 2
// 1625.113 us; speedup vs baseline: 1.5762x; 1.5762x over previous
//
#include <hip/hip_runtime.h>
#include <hip/hip_bf16.h>

typedef __attribute__((ext_vector_type(4))) float f32x4;
typedef __attribute__((ext_vector_type(8))) short short8;
typedef __attribute__((ext_vector_type(8))) __bf16 bf16x8;

union FragU { bf16x8 h; short8 s; };

// ---------------------------------------------------------------------------
// Split-K GEMM: C[M][64] += A[M][K-chunk] (f32) @ BT[64][K-chunk]^T (bf16)
// grid = (rowBlocks, S). Each block: 128 rows x 64 cols over K-chunk,
// 4 waves (one per 32 rows), mfma_f32_16x16x32_bf16, no LDS.
// Partials accumulated into C with atomicAdd (C zeroed before dispatch).
// ---------------------------------------------------------------------------
__global__ __launch_bounds__(256) void gemm_adj_splitk(
    const float* __restrict__ A, const __bf16* __restrict__ BT,
    float* __restrict__ C, int M, int K, int kChunk)
{
  const int wave = threadIdx.x >> 6;
  const int lane = threadIdx.x & 63;
  const int r = lane & 15;   // row-in-mtile / col-in-ntile
  const int g = lane >> 4;   // k-group (0..3)
  const int rowBase = blockIdx.x * 128 + wave * 32;

  const int kLo = blockIdx.y * kChunk;
  const int kHi = min(kLo + kChunk, K);

  f32x4 acc[2][4];
  #pragma unroll
  for (int m = 0; m < 2; ++m)
    #pragma unroll
    for (int n = 0; n < 4; ++n)
      acc[m][n] = (f32x4){0.f, 0.f, 0.f, 0.f};

  const float* aPtr[2];
  #pragma unroll
  for (int m = 0; m < 2; ++m) {
    int row = rowBase + m * 16 + r;
    if (row >= M) row = M - 1;              // clamp; stores are guarded
    aPtr[m] = A + (size_t)row * K + g * 8;
  }
  const __bf16* bPtr[4];
  #pragma unroll
  for (int n = 0; n < 4; ++n)
    bPtr[n] = BT + (size_t)(n * 16 + r) * K + g * 8;

  const int kMain = kLo + ((kHi - kLo) & ~31);

  for (int k0 = kLo; k0 < kMain; k0 += 32) {
    FragU bf[4], af[2];
    #pragma unroll
    for (int n = 0; n < 4; ++n)
      bf[n].s = *(const short8*)(bPtr[n] + k0);
    #pragma unroll
    for (int m = 0; m < 2; ++m) {
      f32x4 a0 = *(const f32x4*)(aPtr[m] + k0);
      f32x4 a1 = *(const f32x4*)(aPtr[m] + k0 + 4);
      bf16x8 h;
      h[0] = (__bf16)a0[0]; h[1] = (__bf16)a0[1];
      h[2] = (__bf16)a0[2]; h[3] = (__bf16)a0[3];
      h[4] = (__bf16)a1[0]; h[5] = (__bf16)a1[1];
      h[6] = (__bf16)a1[2]; h[7] = (__bf16)a1[3];
      af[m].h = h;
    }
    #pragma unroll
    for (int m = 0; m < 2; ++m)
      #pragma unroll
      for (int n = 0; n < 4; ++n)
        acc[m][n] = __builtin_amdgcn_mfma_f32_16x16x32_bf16(
            af[m].s, bf[n].s, acc[m][n], 0, 0, 0);
  }

  if (kMain < kHi) {         // guarded tail; kHi%8==0 so 8-chunks are all-in/out
    const int k0 = kMain;
    const bool ok = (k0 + g * 8) < kHi;
    FragU bf[4], af[2];
    const short8 z = {0, 0, 0, 0, 0, 0, 0, 0};
    #pragma unroll
    for (int n = 0; n < 4; ++n)
      bf[n].s = ok ? *(const short8*)(bPtr[n] + k0) : z;
    #pragma unroll
    for (int m = 0; m < 2; ++m) {
      if (ok) {
        f32x4 a0 = *(const f32x4*)(aPtr[m] + k0);
        f32x4 a1 = *(const f32x4*)(aPtr[m] + k0 + 4);
        bf16x8 h;
        h[0] = (__bf16)a0[0]; h[1] = (__bf16)a0[1];
        h[2] = (__bf16)a0[2]; h[3] = (__bf16)a0[3];
        h[4] = (__bf16)a1[0]; h[5] = (__bf16)a1[1];
        h[6] = (__bf16)a1[2]; h[7] = (__bf16)a1[3];
        af[m].h = h;
      } else {
        af[m].s = z;
      }
    }
    #pragma unroll
    for (int m = 0; m < 2; ++m)
      #pragma unroll
      for (int n = 0; n < 4; ++n)
        acc[m][n] = __builtin_amdgcn_mfma_f32_16x16x32_bf16(
            af[m].s, bf[n].s, acc[m][n], 0, 0, 0);
  }

  // C/D layout: col = lane&15, row = (lane>>4)*4 + reg
  #pragma unroll
  for (int m = 0; m < 2; ++m) {
    #pragma unroll
    for (int j = 0; j < 4; ++j) {
      const int row = rowBase + m * 16 + g * 4 + j;
      if (row < M) {
        #pragma unroll
        for (int n = 0; n < 4; ++n)
          atomicAdd(&C[(size_t)row * 64 + n * 16 + r], acc[m][n][j]);
      }
    }
  }
}

// ---------------------------------------------------------------------------
// Transpose + f32->bf16 convert: in[K][64] f32 -> out[64][K] bf16
// ---------------------------------------------------------------------------
__global__ __launch_bounds__(256) void transpose_cvt(
    const float* __restrict__ in, __bf16* __restrict__ out, int K)
{
  __shared__ float tile[64][65];
  const int t = threadIdx.x;
  const int k0 = blockIdx.x * 64;
  #pragma unroll
  for (int i = 0; i < 4; ++i) {
    int f = t + i * 256;           // float4 index within 64x64 tile
    int k = f >> 4;                // 0..63
    int cc = (f & 15) << 2;        // 0..60
    if (k0 + k < K) {
      f32x4 v = *(const f32x4*)(in + (size_t)(k0 + k) * 64 + cc);
      tile[k][cc + 0] = v[0]; tile[k][cc + 1] = v[1];
      tile[k][cc + 2] = v[2]; tile[k][cc + 3] = v[3];
    }
  }
  __syncthreads();
  const int c = t >> 2;            // 0..63 output row
  const int kc = (t & 3) << 4;     // 0,16,32,48
  #pragma unroll
  for (int h = 0; h < 2; ++h) {
    int kk = kc + h * 8;
    if (k0 + kk < K) {             // 8-chunks are all-in or all-out (K % 8 == 0)
      FragU p;
      #pragma unroll
      for (int j = 0; j < 8; ++j) p.h[j] = (__bf16)tile[kk + j][c];
      *(short8*)(out + (size_t)c * K + k0 + kk) = p.s;
    }
  }
}

// ---------------------------------------------------------------------------
// out[i][c] = LeakyReLU( sum_k (pre[i][k]+self[i][k]) * W[c][k] + 2*b[c] )
// ---------------------------------------------------------------------------
__global__ __launch_bounds__(256) void layer_update(
    const float* __restrict__ pre, const float* __restrict__ self,
    const float* __restrict__ W, const float* __restrict__ b,
    float* __restrict__ out, int M)
{
  __shared__ float xs[4][64];
  const int t = threadIdx.x;
  const int c = t & 63;
  const int grp = t >> 6;
  const int row = blockIdx.x * 4 + grp;
  if (row < M)
    xs[grp][c] = pre[(size_t)row * 64 + c] + self[(size_t)row * 64 + c];
  __syncthreads();
  if (row >= M) return;
  float acc = 0.f;
  const f32x4* Wc = (const f32x4*)(W + c * 64);
  #pragma unroll
  for (int k4 = 0; k4 < 16; ++k4) {
    f32x4 w = Wc[k4];
    acc += xs[grp][k4 * 4 + 0] * w[0] + xs[grp][k4 * 4 + 1] * w[1]
         + xs[grp][k4 * 4 + 2] * w[2] + xs[grp][k4 * 4 + 3] * w[3];
  }
  float v = acc + 2.0f * b[c];
  out[(size_t)row * 64 + c] = (v > 0.f) ? v : 0.01f * v;
}

// ---------------------------------------------------------------------------
// scores[b] = sum_l sum_e u_l[uid[b]][e]*m_l[mid[b]][e]*outW[l*64+e] + outb
// ---------------------------------------------------------------------------
__global__ __launch_bounds__(256) void gather_score(
    const int* __restrict__ uid, const int* __restrict__ mid,
    const float* __restrict__ u0, const float* __restrict__ u1,
    const float* __restrict__ u2, const float* __restrict__ u3,
    const float* __restrict__ m0, const float* __restrict__ m1,
    const float* __restrict__ m2, const float* __restrict__ m3,
    const float* __restrict__ oW, const float* __restrict__ ob,
    float* __restrict__ scores, int B)
{
  const int wave = threadIdx.x >> 6;
  const int lane = threadIdx.x & 63;
  const int b = blockIdx.x * 4 + wave;
  if (b >= B) return;
  const size_t ub = (size_t)uid[b] * 64 + lane;
  const size_t mb = (size_t)mid[b] * 64 + lane;
  float acc = u0[ub] * m0[mb] * oW[lane]
            + u1[ub] * m1[mb] * oW[64 + lane]
            + u2[ub] * m2[mb] * oW[128 + lane]
            + u3[ub] * m3[mb] * oW[192 + lane];
  #pragma unroll
  for (int off = 32; off > 0; off >>= 1)
    acc += __shfl_down(acc, off, 64);
  if (lane == 0) scores[b] = acc + ob[0];
}

// ---------------------------------------------------------------------------
extern "C" void kernel_launch(void* const* d_in, const int* in_sizes, int n_in,
                              void* d_out, int out_size, void* d_ws, size_t ws_size,
                              hipStream_t stream)
{
  const float* user_adj  = (const float*)d_in[0];
  const float* movie_adj = (const float*)d_in[1];
  const int*   user_id   = (const int*)d_in[2];
  const int*   movie_id  = (const int*)d_in[3];
  const float* user_emb  = (const float*)d_in[4];
  const float* movie_emb = (const float*)d_in[5];
  const float* user_Ws   = (const float*)d_in[6];
  const float* user_bs   = (const float*)d_in[7];
  const float* movie_Ws  = (const float*)d_in[8];
  const float* movie_bs  = (const float*)d_in[9];
  const float* out_W     = (const float*)d_in[10];
  const float* out_b     = (const float*)d_in[11];

  const int NU = 20000, NM = 10000, E = 64, B = 8192;

  char* ws = (char*)d_ws;
  float*  u_pre = (float*)(ws);                   // 20000*64 f32 = 5,120,000 B
  float*  m_pre = (float*)(ws + 5120000);         // 10000*64 f32 = 2,560,000 B
  float*  u1    = (float*)(ws + 7680000);         // 5,120,000 B
  float*  u2    = (float*)(ws + 12800000);        // 5,120,000 B
  float*  m1    = (float*)(ws + 17920000);        // 2,560,000 B
  float*  m2    = (float*)(ws + 20480000);        // 2,560,000 B
  __bf16* uT    = (__bf16*)(ws + 23040000);       // 64*20000 bf16 = 2,560,000 B
  __bf16* mT    = (__bf16*)(ws + 25600000);       // 64*10000 bf16 = 1,280,000 B

  float* scores = (float*)d_out;
  float* u3 = scores + B;            // [20000,64]
  float* m3 = u3 + (size_t)NU * E;   // [10000,64]

  // split-K config: chunk=1280 k-elements (multiple of 32)
  const int KCH = 1280;
  const int SU = (NM + KCH - 1) / KCH;   // 8 splits for K=10000
  const int SM = (NU + KCH - 1) / KCH;   // 16 splits for K=20000

  const float* uCur = user_emb;
  const float* mCur = movie_emb;
  for (int l = 0; l < 3; ++l) {
    float* uNext = (l == 0) ? u1 : (l == 1) ? u2 : u3;
    float* mNext = (l == 0) ? m1 : (l == 1) ? m2 : m3;

    hipMemsetAsync(u_pre, 0, (size_t)NU * E * sizeof(float), stream);
    hipMemsetAsync(m_pre, 0, (size_t)NM * E * sizeof(float), stream);

    transpose_cvt<<<(NM + 63) / 64, 256, 0, stream>>>(mCur, mT, NM);
    transpose_cvt<<<(NU + 63) / 64, 256, 0, stream>>>(uCur, uT, NU);

    dim3 gU((NU + 127) / 128, SU);
    gemm_adj_splitk<<<gU, 256, 0, stream>>>(user_adj, mT, u_pre, NU, NM, KCH);
    dim3 gM((NM + 127) / 128, SM);
    gemm_adj_splitk<<<gM, 256, 0, stream>>>(movie_adj, uT, m_pre, NM, NU, KCH);

    layer_update<<<(NU + 3) / 4, 256, 0, stream>>>(
        u_pre, uCur, user_Ws + (size_t)l * E * E, user_bs + (size_t)l * E, uNext, NU);
    layer_update<<<(NM + 3) / 4, 256, 0, stream>>>(
        m_pre, mCur, movie_Ws + (size_t)l * E * E, movie_bs + (size_t)l * E, mNext, NM);
    uCur = uNext; mCur = mNext;
  }
  gather_score<<<(B + 3) / 4, 256, 0, stream>>>(
      user_id, movie_id, user_emb, u1, u2, u3,
      movie_emb, m1, m2, m3, out_W, out_b, scores, B);
}

// Round 3
// 1237.209 us; speedup vs baseline: 2.0704x; 1.3135x over previous
//
#include <hip/hip_runtime.h>
#include <hip/hip_bf16.h>

typedef __attribute__((ext_vector_type(4))) float f32x4;
typedef __attribute__((ext_vector_type(8))) short short8;
typedef __attribute__((ext_vector_type(8))) __bf16 bf16x8;

union FragU { bf16x8 h; short8 s; };

typedef const __attribute__((address_space(1))) void gvoid_t;
typedef __attribute__((address_space(3))) void lvoid_t;

static __device__ __forceinline__ void gload16(const void* g, void* l) {
  // async global->LDS, 16B per lane; LDS dest is wave-uniform base + lane*16
  __builtin_amdgcn_global_load_lds((gvoid_t*)g, (lvoid_t*)l, 16, 0, 0);
}

// ---------------------------------------------------------------------------
// Fused split-K GEMM pair: C[M][64] += A[M][kslice] (f32) @ BT[64][kslice]^T
// (bf16). One dispatch covers user-gemm blocks then movie-gemm blocks.
// Per block: 128 rows x 64 cols, k-tile 32, LDS double-buffered staging via
// global_load_lds. A-tile uses XOR granule swizzle (src-side + read-side,
// linear LDS dest) to balance ds_read_b128 banks. Partials atomicAdd'ed.
// ---------------------------------------------------------------------------
__global__ __launch_bounds__(256) void gemm_fused(
    const float* __restrict__ Au, const __bf16* __restrict__ BTu,
    float* __restrict__ Cu, int Mu, int Ku,
    const float* __restrict__ Am, const __bf16* __restrict__ BTm,
    float* __restrict__ Cm, int Mm, int Km,
    int nbU, int rbU, int rbM, int kChunk)
{
  __shared__ float  sA[2][128 * 32];   // 2 x 16 KB
  __shared__ __bf16 sB[2][64 * 32];    // 2 x 4 KB

  const int t = threadIdx.x;
  const int w = t >> 6;
  const int lane = t & 63;
  const int r = lane & 15;
  const int g = lane >> 4;

  const float* A; const __bf16* BT; float* C; int M, K, rowBlk, split;
  {
    int bx = blockIdx.x;
    if (bx < nbU) {
      A = Au; BT = BTu; C = Cu; M = Mu; K = Ku;
      rowBlk = bx % rbU; split = bx / rbU;
    } else {
      int b2 = bx - nbU;
      A = Am; BT = BTm; C = Cm; M = Mm; K = Km;
      rowBlk = b2 % rbM; split = b2 / rbM;
    }
  }
  const int rowBase = rowBlk * 128;
  const int kLo = split * kChunk;
  const int kHi = min(kLo + kChunk, K);
  const int nt = (kHi - kLo) >> 5;     // full 32-k tiles

  f32x4 acc[2][4];
  #pragma unroll
  for (int m = 0; m < 2; ++m)
    #pragma unroll
    for (int n = 0; n < 4; ++n)
      acc[m][n] = (f32x4){0.f, 0.f, 0.f, 0.f};

  // ---- staging helper (all 256 threads) ----
  auto stage = [&](int buf, int k0) {
    #pragma unroll
    for (int i = 0; i < 4; ++i) {
      int idx = i * 256 + t;
      int rr = idx >> 3;               // local row 0..127
      int p  = idx & 7;                // 16B granule within 128B row-span
      int rowg = rowBase + rr; if (rowg > M - 1) rowg = M - 1;
      // linear LDS dest; source pre-swizzled so read-side XOR is balanced
      gload16(A + (size_t)rowg * K + k0 + ((p ^ (rr & 7)) << 2),
              &sA[buf][i * 1024 + w * 256]);
    }
    {
      int row = t >> 2;                // 0..63
      int p = t & 3;
      gload16(BT + (size_t)row * K + k0 + p * 8,
              &sB[buf][w * 512]);
    }
  };

  int cur = 0;
  stage(0, kLo);
  __syncthreads();

  for (int tt = 0; tt < nt; ++tt) {
    if (tt + 1 < nt) stage(cur ^ 1, kLo + (tt + 1) * 32);

    FragU bfr[4], afr[2];
    #pragma unroll
    for (int n = 0; n < 4; ++n)
      bfr[n].s = *(const short8*)&sB[cur][(n * 16 + r) * 32 + g * 8];
    #pragma unroll
    for (int m = 0; m < 2; ++m) {
      const int rr = w * 32 + m * 16 + r;
      const float* rowp = &sA[cur][rr * 32];
      f32x4 a0 = *(const f32x4*)(rowp + (((2 * g)     ^ (r & 7)) << 2));
      f32x4 a1 = *(const f32x4*)(rowp + (((2 * g + 1) ^ (r & 7)) << 2));
      bf16x8 h;
      h[0] = (__bf16)a0[0]; h[1] = (__bf16)a0[1];
      h[2] = (__bf16)a0[2]; h[3] = (__bf16)a0[3];
      h[4] = (__bf16)a1[0]; h[5] = (__bf16)a1[1];
      h[6] = (__bf16)a1[2]; h[7] = (__bf16)a1[3];
      afr[m].h = h;
    }
    #pragma unroll
    for (int m = 0; m < 2; ++m)
      #pragma unroll
      for (int n = 0; n < 4; ++n)
        acc[m][n] = __builtin_amdgcn_mfma_f32_16x16x32_bf16(
            afr[m].s, bfr[n].s, acc[m][n], 0, 0, 0);

    __syncthreads();
    cur ^= 1;
  }

  // ---- ragged tail (<32 k), register path (user last split only: 16 k) ----
  const int kMain = kLo + nt * 32;
  if (kMain < kHi) {
    const bool ok = (kMain + g * 8) < kHi;
    const short8 z = {0, 0, 0, 0, 0, 0, 0, 0};
    FragU bfr[4], afr[2];
    #pragma unroll
    for (int n = 0; n < 4; ++n)
      bfr[n].s = ok ? *(const short8*)(BT + (size_t)(n * 16 + r) * K + kMain + g * 8) : z;
    #pragma unroll
    for (int m = 0; m < 2; ++m) {
      if (ok) {
        int rowg = rowBase + w * 32 + m * 16 + r; if (rowg > M - 1) rowg = M - 1;
        const float* ap = A + (size_t)rowg * K + kMain + g * 8;
        f32x4 a0 = *(const f32x4*)(ap);
        f32x4 a1 = *(const f32x4*)(ap + 4);
        bf16x8 h;
        h[0] = (__bf16)a0[0]; h[1] = (__bf16)a0[1];
        h[2] = (__bf16)a0[2]; h[3] = (__bf16)a0[3];
        h[4] = (__bf16)a1[0]; h[5] = (__bf16)a1[1];
        h[6] = (__bf16)a1[2]; h[7] = (__bf16)a1[3];
        afr[m].h = h;
      } else {
        afr[m].s = z;
      }
    }
    #pragma unroll
    for (int m = 0; m < 2; ++m)
      #pragma unroll
      for (int n = 0; n < 4; ++n)
        acc[m][n] = __builtin_amdgcn_mfma_f32_16x16x32_bf16(
            afr[m].s, bfr[n].s, acc[m][n], 0, 0, 0);
  }

  // ---- epilogue: C/D layout col=lane&15, row=(lane>>4)*4+reg ----
  #pragma unroll
  for (int m = 0; m < 2; ++m) {
    #pragma unroll
    for (int j = 0; j < 4; ++j) {
      const int row = rowBase + w * 32 + m * 16 + g * 4 + j;
      if (row < M) {
        #pragma unroll
        for (int n = 0; n < 4; ++n)
          atomicAdd(&C[(size_t)row * 64 + n * 16 + r], acc[m][n][j]);
      }
    }
  }
}

// ---------------------------------------------------------------------------
// Transpose + f32->bf16 convert: in[K][64] f32 -> out[64][K] bf16
// ---------------------------------------------------------------------------
__global__ __launch_bounds__(256) void transpose_cvt(
    const float* __restrict__ in, __bf16* __restrict__ out, int K)
{
  __shared__ float tile[64][65];
  const int t = threadIdx.x;
  const int k0 = blockIdx.x * 64;
  #pragma unroll
  for (int i = 0; i < 4; ++i) {
    int f = t + i * 256;
    int k = f >> 4;
    int cc = (f & 15) << 2;
    if (k0 + k < K) {
      f32x4 v = *(const f32x4*)(in + (size_t)(k0 + k) * 64 + cc);
      tile[k][cc + 0] = v[0]; tile[k][cc + 1] = v[1];
      tile[k][cc + 2] = v[2]; tile[k][cc + 3] = v[3];
    }
  }
  __syncthreads();
  const int c = t >> 2;
  const int kc = (t & 3) << 4;
  #pragma unroll
  for (int h = 0; h < 2; ++h) {
    int kk = kc + h * 8;
    if (k0 + kk < K) {
      FragU p;
      #pragma unroll
      for (int j = 0; j < 8; ++j) p.h[j] = (__bf16)tile[kk + j][c];
      *(short8*)(out + (size_t)c * K + k0 + kk) = p.s;
    }
  }
}

// ---------------------------------------------------------------------------
// out[i][c] = LeakyReLU( sum_k (pre[i][k]+self[i][k]) * W[c][k] + 2*b[c] )
// ---------------------------------------------------------------------------
__global__ __launch_bounds__(256) void layer_update(
    const float* __restrict__ pre, const float* __restrict__ self,
    const float* __restrict__ W, const float* __restrict__ b,
    float* __restrict__ out, int M)
{
  __shared__ float xs[4][64];
  const int t = threadIdx.x;
  const int c = t & 63;
  const int grp = t >> 6;
  const int row = blockIdx.x * 4 + grp;
  if (row < M)
    xs[grp][c] = pre[(size_t)row * 64 + c] + self[(size_t)row * 64 + c];
  __syncthreads();
  if (row >= M) return;
  float acc = 0.f;
  const f32x4* Wc = (const f32x4*)(W + c * 64);
  #pragma unroll
  for (int k4 = 0; k4 < 16; ++k4) {
    f32x4 w = Wc[k4];
    acc += xs[grp][k4 * 4 + 0] * w[0] + xs[grp][k4 * 4 + 1] * w[1]
         + xs[grp][k4 * 4 + 2] * w[2] + xs[grp][k4 * 4 + 3] * w[3];
  }
  float v = acc + 2.0f * b[c];
  out[(size_t)row * 64 + c] = (v > 0.f) ? v : 0.01f * v;
}

// ---------------------------------------------------------------------------
__global__ __launch_bounds__(256) void gather_score(
    const int* __restrict__ uid, const int* __restrict__ mid,
    const float* __restrict__ u0, const float* __restrict__ u1,
    const float* __restrict__ u2, const float* __restrict__ u3,
    const float* __restrict__ m0, const float* __restrict__ m1,
    const float* __restrict__ m2, const float* __restrict__ m3,
    const float* __restrict__ oW, const float* __restrict__ ob,
    float* __restrict__ scores, int B)
{
  const int wave = threadIdx.x >> 6;
  const int lane = threadIdx.x & 63;
  const int b = blockIdx.x * 4 + wave;
  if (b >= B) return;
  const size_t ub = (size_t)uid[b] * 64 + lane;
  const size_t mb = (size_t)mid[b] * 64 + lane;
  float acc = u0[ub] * m0[mb] * oW[lane]
            + u1[ub] * m1[mb] * oW[64 + lane]
            + u2[ub] * m2[mb] * oW[128 + lane]
            + u3[ub] * m3[mb] * oW[192 + lane];
  #pragma unroll
  for (int off = 32; off > 0; off >>= 1)
    acc += __shfl_down(acc, off, 64);
  if (lane == 0) scores[b] = acc + ob[0];
}

// ---------------------------------------------------------------------------
extern "C" void kernel_launch(void* const* d_in, const int* in_sizes, int n_in,
                              void* d_out, int out_size, void* d_ws, size_t ws_size,
                              hipStream_t stream)
{
  const float* user_adj  = (const float*)d_in[0];
  const float* movie_adj = (const float*)d_in[1];
  const int*   user_id   = (const int*)d_in[2];
  const int*   movie_id  = (const int*)d_in[3];
  const float* user_emb  = (const float*)d_in[4];
  const float* movie_emb = (const float*)d_in[5];
  const float* user_Ws   = (const float*)d_in[6];
  const float* user_bs   = (const float*)d_in[7];
  const float* movie_Ws  = (const float*)d_in[8];
  const float* movie_bs  = (const float*)d_in[9];
  const float* out_W     = (const float*)d_in[10];
  const float* out_b     = (const float*)d_in[11];

  const int NU = 20000, NM = 10000, E = 64, B = 8192;

  char* ws = (char*)d_ws;
  float*  u_pre = (float*)(ws);                   // 5,120,000 B
  float*  m_pre = (float*)(ws + 5120000);         // 2,560,000 B
  float*  u1    = (float*)(ws + 7680000);
  float*  u2    = (float*)(ws + 12800000);
  float*  m1    = (float*)(ws + 17920000);
  float*  m2    = (float*)(ws + 20480000);
  __bf16* uT    = (__bf16*)(ws + 23040000);       // [64][20000] bf16
  __bf16* mT    = (__bf16*)(ws + 25600000);       // [64][10000] bf16

  float* scores = (float*)d_out;
  float* u3 = scores + B;
  float* m3 = u3 + (size_t)NU * E;

  const int KCH = 1280;
  const int SU = (NM + KCH - 1) / KCH;   // 8  (user gemm K = NM)
  const int SM = (NU + KCH - 1) / KCH;   // 16 (movie gemm K = NU)
  const int rbU = (NU + 127) / 128;      // 157
  const int rbM = (NM + 127) / 128;      // 79
  const int nbU = rbU * SU;              // 1256
  const int nbM = rbM * SM;              // 1264

  const float* uCur = user_emb;
  const float* mCur = movie_emb;
  for (int l = 0; l < 3; ++l) {
    float* uNext = (l == 0) ? u1 : (l == 1) ? u2 : u3;
    float* mNext = (l == 0) ? m1 : (l == 1) ? m2 : m3;

    hipMemsetAsync(u_pre, 0, (size_t)NU * E * sizeof(float), stream);
    hipMemsetAsync(m_pre, 0, (size_t)NM * E * sizeof(float), stream);

    transpose_cvt<<<(NM + 63) / 64, 256, 0, stream>>>(mCur, mT, NM);
    transpose_cvt<<<(NU + 63) / 64, 256, 0, stream>>>(uCur, uT, NU);

    gemm_fused<<<nbU + nbM, 256, 0, stream>>>(
        user_adj, mT, u_pre, NU, NM,
        movie_adj, uT, m_pre, NM, NU,
        nbU, rbU, rbM, KCH);

    layer_update<<<(NU + 3) / 4, 256, 0, stream>>>(
        u_pre, uCur, user_Ws + (size_t)l * E * E, user_bs + (size_t)l * E, uNext, NU);
    layer_update<<<(NM + 3) / 4, 256, 0, stream>>>(
        m_pre, mCur, movie_Ws + (size_t)l * E * E, movie_bs + (size_t)l * E, mNext, NM);
    uCur = uNext; mCur = mNext;
  }
  gather_score<<<(B + 3) / 4, 256, 0, stream>>>(
      user_id, movie_id, user_emb, u1, u2, u3,
      movie_emb, m1, m2, m3, out_W, out_b, scores, B);
}